// Round 6
// baseline (231.077 us; speedup 1.0000x reference)
//
#include <hip/hip_runtime.h>
#include <math.h>

// Problem constants
#define B_  8192
#define F_  32
#define V_  64
#define C_  32
#define KP_ 7
#define EPS_ 1e-6f

// ws layout (floats):
//  [0,248)           : w[f][k]  (31 x 8 gumbel-softmax weights); [248,256) zeros
//  [256,288)         : offc[c]
//  [512,66048)       : G[j][v][c]   (folded t0/self/pair-lse table, 256 KB)
//  [66048,1843712)   : partial exp-sums, 4 banks of [fk][xc][c];
//                      foldg does log(b0+b1+b2+b3)
//  [1843712,3940864) : pair partials, [sample][group][c] float4s (8 MB)
#define WS_OFF  256
#define WS_G    512
#define WS_LSE  66048
#define LSE_BANK4 111104    // bank stride in float4 units (217*64*8)
#define WS_PART 1843712

#define NBLK_LSE 868
#define NBLK_PAIR 2048      // 256 sample-chunks x 8 entry-groups
#define NBLK_FOLD 64

__device__ const int d_split[9] = {0, 25, 50, 74, 99, 123, 148, 172, 196};

// ---- Kernel 1: lse streaming (868 blocks) + prep (block 868) --------------
// Streams all of pt once (leaves it L3-resident for the gather pass).
__global__ __launch_bounds__(256)
void lse_prep_kernel(const float* __restrict__ pt,
                     const float* __restrict__ cl, const float* __restrict__ t0,
                     const float* __restrict__ st, const float* __restrict__ sl,
                     const float* __restrict__ un, float* __restrict__ ws) {
    if (blockIdx.x < NBLK_LSE) {
        int fk = blockIdx.x >> 2;     // 0..216
        int qa = blockIdx.x & 3;      // which 16-slice of the a-axis
        int t  = threadIdx.x;
        const float4* __restrict__ p =
            (const float4*)(pt + (size_t)fk * (V_ * V_ * C_)
                               + (size_t)qa * 16 * (V_ * C_));
        const float4* p0 = p + t;
        const float4* p1 = p + 256 + t;
        float4 s0 = make_float4(0.f, 0.f, 0.f, 0.f);
        float4 s1 = make_float4(0.f, 0.f, 0.f, 0.f);
        #pragma unroll 4
        for (int a = 0; a < 16; a++) {
            float4 l0 = p0[a * 512];
            float4 l1 = p1[a * 512];
            s0.x += __expf(l0.x); s0.y += __expf(l0.y);
            s0.z += __expf(l0.z); s0.w += __expf(l0.w);
            s1.x += __expf(l1.x); s1.y += __expf(l1.y);
            s1.z += __expf(l1.z); s1.w += __expf(l1.w);
        }
        float4* lseP = (float4*)(ws + WS_LSE) + (size_t)qa * LSE_BANK4;
        lseP[fk * 512 + t]       = s0;
        lseP[fk * 512 + 256 + t] = s1;
    } else {
        // ---------- prep: ws weights (foldg) + offc (mainG) ----------
        __shared__ float gl[31][8];
        __shared__ float wsm[31][8];
        __shared__ float lsf[31][32];
        int tid = threadIdx.x;
        if (tid < 248) {
            int f = tid >> 3, k = tid & 7;
            int kmax = min(f + 1, KP_);
            bool valid = (k <= kmax);
            float u = un[tid];
            float g = -__logf(-__logf(u + EPS_) + EPS_);
            gl[f][k] = valid ? (sl[tid] + g) : -INFINITY;
        } else {
            ws[tid] = 0.f;
        }
        __syncthreads();
        if (tid < 248) {
            int f = tid >> 3, k = tid & 7;
            float m = -INFINITY;
            #pragma unroll
            for (int j = 0; j < 8; j++) m = fmaxf(m, gl[f][j]);
            float s = 0.f;
            #pragma unroll
            for (int j = 0; j < 8; j++) s += __expf(gl[f][j] - m);
            float wv = __expf(gl[f][k] - m) / s;
            wsm[f][k] = wv;
            ws[tid] = wv;
        }
        for (int i = tid; i < 992; i += 256) {   // lse over self_tables v-axis
            int f = i >> 5, c = i & 31;
            float s = 0.f;
            #pragma unroll 8
            for (int v = 0; v < V_; v++) s += __expf(st[(f * V_ + v) * C_ + c]);
            lsf[f][c] = __logf(s);
        }
        __syncthreads();
        if (tid < 32) {
            int c = tid;
            float scl = 0.f;
            #pragma unroll
            for (int j = 0; j < C_; j++) scl += __expf(cl[j]);
            float lse_cl = __logf(scl);
            float s0 = 0.f;
            #pragma unroll 8
            for (int v = 0; v < V_; v++) s0 += __expf(t0[v * C_ + c]);
            float lse_t0 = __logf(s0);
            float acc = cl[c] - lse_cl - lse_t0;
            for (int f = 0; f < 31; f++) acc -= wsm[f][0] * lsf[f][c];
            ws[WS_OFF + c] = acc;
        }
    }
}

// ---- Kernel 2: entry-major pair gather (XCD-affine) + foldg tail ----------
// Blocks [0,2048): group g = blockIdx&7 (XCD round-robin), chunk = blockIdx>>3.
// Each block: 32 samples x 25 entries of ITS group. All 256 blocks of one
// XCD are co-resident and walk the same ~13 MB entry subset in lockstep ->
// instantaneous L2 working set ~1 MB; each 524 KB fk sub-table crosses
// L3->L2 once. (Round-5 sample-major form kept the full 113.8 MB hot ->
// 2.8 TB/s L3-random service was the limiter.)
// Blocks [2048,2112): foldg (depends only on lse+prep, both complete).
__global__ __launch_bounds__(256)
void pair_fold_kernel(const int* __restrict__ x, const float* __restrict__ pt,
                      const float* __restrict__ t0, const float* __restrict__ st,
                      const float* __restrict__ sl, const float* __restrict__ un,
                      float* __restrict__ ws) {
    if (blockIdx.x < NBLK_PAIR) {
        __shared__ int   xsh[32][33];
        __shared__ float wsh[256];
        __shared__ int   etab[200];
        __shared__ float gl[31][8];
        int tid = threadIdx.x;
        int g     = blockIdx.x & 7;
        int chunk = blockIdx.x >> 3;
        int s0    = chunk * 32;
        for (int i = tid; i < 1024; i += 256)
            xsh[i >> 5][i & 31] = x[s0 * 32 + i];
        if (tid < 248) {
            int f = tid >> 3, k = tid & 7;
            int kmax = min(f + 1, KP_);
            bool valid = (k <= kmax);
            float u = un[tid];
            float gg = -__logf(-__logf(u + EPS_) + EPS_);
            gl[f][k] = valid ? (sl[tid] + gg) : -INFINITY;
        }
        if (tid < 200) {
            int q = tid / 25, i = tid % 25;
            int e = d_split[q] + i;
            int packed;
            if (e < d_split[q + 1]) {
                int f = 0, base = 0;
                for (;;) { int cnt = min(f + 1, KP_); if (e < base + cnt) break; base += cnt; f++; }
                int k = e - base;
                packed = ((f * 8 + k + 1) << 20) | ((f * KP_ + k) << 12) | ((f + 1) << 6) | (f - k);
            } else {
                packed = (248 << 20);   // weight=0 pad entry
            }
            etab[tid] = packed;
        }
        __syncthreads();
        if (tid < 248) {
            int f = tid >> 3;
            float m = -INFINITY;
            #pragma unroll
            for (int j = 0; j < 8; j++) m = fmaxf(m, gl[f][j]);
            float s = 0.f;
            #pragma unroll
            for (int j = 0; j < 8; j++) s += __expf(gl[f][j] - m);
            wsh[tid] = __expf(gl[f][tid & 7] - m) / s;
        } else {
            wsh[tid] = 0.f;
        }
        __syncthreads();

        int s  = tid >> 3;          // 0..31: sample within chunk
        int c4 = tid & 7;
        const int* xrow = xsh[s];
        const float* __restrict__ ptb = pt + c4 * 4;
        float4 acc = make_float4(0.f, 0.f, 0.f, 0.f);

        int beg = g * 25;
        #pragma unroll
        for (int ch = 0; ch < 5; ch++) {
            float4 pv[5];
            float  wt[5];
            #pragma unroll
            for (int i = 0; i < 5; i++) {
                int pk = etab[beg + ch * 5 + i];
                int ci = pk & 63, fi = (pk >> 6) & 63;
                int fk = (pk >> 12) & 255, widx = (pk >> 20) & 255;
                int xv = xrow[fi], xc = xrow[ci];
                pv[i] = *(const float4*)(ptb + ((size_t)(fk * V_ + xv) * V_ + xc) * C_);
                wt[i] = wsh[widx];
            }
            #pragma unroll
            for (int i = 0; i < 5; i++) {
                acc.x += wt[i] * pv[i].x; acc.y += wt[i] * pv[i].y;
                acc.z += wt[i] * pv[i].z; acc.w += wt[i] * pv[i].w;
            }
        }
        // partial: [sample][group][c4] float4
        ((float4*)(ws + WS_PART))[(size_t)(s0 + s) * 64 + g * 8 + c4] = acc;
    } else {
        // ---------- foldg: G[j][v][c] = t0/self - sum_k w*log(sum banks) ----
        int idx = (blockIdx.x - NBLK_PAIR) * 256 + threadIdx.x;
        int c4 = idx & 7, v = (idx >> 3) & 63, j = idx >> 9;    // j 0..31
        int nk = min(KP_, 31 - j);
        const float4* lse4 = (const float4*)(ws + WS_LSE);
        float4 gv;
        if (j == 0) {
            gv = ((const float4*)t0)[v * 8 + c4];
        } else {
            float w0 = ws[(j - 1) * 8];
            float4 sv = ((const float4*)st)[((j - 1) * V_ + v) * 8 + c4];
            gv.x = w0 * sv.x; gv.y = w0 * sv.y; gv.z = w0 * sv.z; gv.w = w0 * sv.w;
        }
        for (int k = 0; k < nk; k++) {
            int f = j + k;
            float wv = ws[f * 8 + k + 1];
            int iq = ((f * KP_ + k) * V_ + v) * 8 + c4;
            float4 sa = lse4[iq];
            float4 sb = lse4[1 * LSE_BANK4 + iq];
            float4 sc = lse4[2 * LSE_BANK4 + iq];
            float4 sd = lse4[3 * LSE_BANK4 + iq];
            gv.x -= wv * __logf(sa.x + sb.x + sc.x + sd.x);
            gv.y -= wv * __logf(sa.y + sb.y + sc.y + sd.y);
            gv.z -= wv * __logf(sa.z + sb.z + sc.z + sd.z);
            gv.w -= wv * __logf(sa.w + sb.w + sc.w + sd.w);
        }
        ((float4*)(ws + WS_G))[idx] = gv;
    }
}

// ---- Kernel 3: epilogue -- sum 8 group partials + offc + G gathers --------
__global__ __launch_bounds__(256)
void maing_kernel(const int* __restrict__ x, const float* __restrict__ ws,
                  float* __restrict__ out) {
    __shared__ int    xsh[32][33];
    __shared__ float4 offv[8];
    int tid = threadIdx.x;
    int rbase = blockIdx.x * 32;
    for (int i = tid; i < 1024; i += 256) {
        int rr = i >> 5, jj = i & 31;
        xsh[rr][jj] = x[(rbase + rr) * 32 + jj];
    }
    if (tid < 8) offv[tid] = ((const float4*)(ws + WS_OFF))[tid];
    __syncthreads();
    int r = tid >> 3, c4 = tid & 7;
    const float4* __restrict__ G4 = (const float4*)(ws + WS_G);
    float4 acc = offv[c4];
    const float4* __restrict__ pp =
        (const float4*)(ws + WS_PART) + (size_t)(rbase + r) * 64 + c4;
    #pragma unroll
    for (int g = 0; g < 8; g++) {
        float4 t = pp[g * 8];
        acc.x += t.x; acc.y += t.y; acc.z += t.z; acc.w += t.w;
    }
    #pragma unroll 8
    for (int j = 0; j < 32; j++) {
        float4 gv = G4[(j * V_ + xsh[r][j]) * 8 + c4];
        acc.x += gv.x; acc.y += gv.y; acc.z += gv.z; acc.w += gv.w;
    }
    ((float4*)out)[(rbase + r) * 8 + c4] = acc;
}

extern "C" void kernel_launch(void* const* d_in, const int* in_sizes, int n_in,
                              void* d_out, int out_size, void* d_ws, size_t ws_size,
                              hipStream_t stream) {
    const int*   x   = (const int*)  d_in[0];
    // d_in[1] = training (unused)
    const float* cl  = (const float*)d_in[2];
    const float* t0  = (const float*)d_in[3];
    const float* st  = (const float*)d_in[4];
    const float* pt  = (const float*)d_in[5];
    const float* sl  = (const float*)d_in[6];
    const float* un  = (const float*)d_in[7];
    // d_in[8] cond_index, d_in[9] valid_mask: deterministic, computed analytically
    float* ws  = (float*)d_ws;
    float* out = (float*)d_out;

    lse_prep_kernel<<<NBLK_LSE + 1, 256, 0, stream>>>(pt, cl, t0, st, sl, un, ws);
    pair_fold_kernel<<<NBLK_PAIR + NBLK_FOLD, 256, 0, stream>>>(x, pt, t0, st, sl, un, ws);
    maing_kernel<<<256, 256, 0, stream>>>(x, ws, out);
}

// Round 7
// 223.205 us; speedup vs baseline: 1.0353x; 1.0353x over previous
//
#include <hip/hip_runtime.h>
#include <math.h>

// Problem constants
#define B_  8192
#define F_  32
#define V_  64
#define C_  32
#define KP_ 7
#define EPS_ 1e-6f

typedef float f4 __attribute__((ext_vector_type(4)));

// ws layout (floats):
//  [0,248)           : w[f][k]  (31 x 8 gumbel-softmax weights); [248,256) zeros
//  [256,288)         : offc[c]
//  [512,66048)       : G[j][v][c]   (folded t0/self/pair-lse table, 256 KB)
//  [66048,1843712)   : partial exp-sums, 4 banks of [fk][xc][c];
//                      foldg does log(b0+b1+b2+b3)
//  [1843712,2105856) : pair-gather partial accs, [sample][c] (1 MB)
#define WS_OFF  256
#define WS_G    512
#define WS_LSE  66048
#define LSE_BANK4 111104    // bank stride in float4 units (217*64*8)
#define WS_PART 1843712

// Fused kernel decomposition (round-5 form — best measured, 223.7 us):
//  blocks [0,868)        : lse streaming (fk, quarter-of-a-axis)
//  block  868            : prep (weights to ws, offc)
//  blocks [869, 869+2048): pair-gather (4 samples each), self-contained
#define NBLK_LSE 868
#define NBLK_PAIR 2048

__device__ const int d_split[9] = {0, 25, 50, 74, 99, 123, 148, 172, 196};

// ---- Kernel 1 (fused): lse streaming + prep + pair-gather.
// lse (BW-bound) and pair (request-rate-bound) overlap via co-residency.
// NEW vs round 5: the lse stream (read-once, 113.8 MB) uses NON-TEMPORAL
// loads, and its partial sums use non-temporal stores, so the stream does
// not displace pair-gather lines from L2 MRU while both phases share CUs.
__global__ __launch_bounds__(256)
void fused_kernel(const int* __restrict__ x, const float* __restrict__ pt,
                  const float* __restrict__ cl, const float* __restrict__ t0,
                  const float* __restrict__ st, const float* __restrict__ sl,
                  const float* __restrict__ un, float* __restrict__ ws) {
    if (blockIdx.x < NBLK_LSE) {
        // ---------- lse: exp-sum over pair self-axis, contiguous stream ----
        int fk = blockIdx.x >> 2;     // 0..216
        int qa = blockIdx.x & 3;      // which 16-slice of the a-axis
        int t  = threadIdx.x;
        const f4* __restrict__ p =
            (const f4*)(pt + (size_t)fk * (V_ * V_ * C_)
                           + (size_t)qa * 16 * (V_ * C_));
        const f4* p0 = p + t;
        const f4* p1 = p + 256 + t;
        f4 s0 = (f4)(0.f);
        f4 s1 = (f4)(0.f);
        #pragma unroll 4
        for (int a = 0; a < 16; a++) {
            f4 l0 = __builtin_nontemporal_load(p0 + a * 512);
            f4 l1 = __builtin_nontemporal_load(p1 + a * 512);
            s0.x += __expf(l0.x); s0.y += __expf(l0.y);
            s0.z += __expf(l0.z); s0.w += __expf(l0.w);
            s1.x += __expf(l1.x); s1.y += __expf(l1.y);
            s1.z += __expf(l1.z); s1.w += __expf(l1.w);
        }
        f4* lseP = (f4*)(ws + WS_LSE) + (size_t)qa * LSE_BANK4;
        __builtin_nontemporal_store(s0, lseP + fk * 512 + t);
        __builtin_nontemporal_store(s1, lseP + fk * 512 + 256 + t);
    } else if (blockIdx.x == NBLK_LSE) {
        // ---------- prep: ws weights (foldg) + offc (mainG) ----------
        __shared__ float gl[31][8];
        __shared__ float wsm[31][8];
        __shared__ float lsf[31][32];
        int tid = threadIdx.x;
        if (tid < 248) {
            int f = tid >> 3, k = tid & 7;
            int kmax = min(f + 1, KP_);
            bool valid = (k <= kmax);
            float u = un[tid];
            float g = -__logf(-__logf(u + EPS_) + EPS_);
            gl[f][k] = valid ? (sl[tid] + g) : -INFINITY;
        } else {
            ws[tid] = 0.f;
        }
        __syncthreads();
        if (tid < 248) {
            int f = tid >> 3, k = tid & 7;
            float m = -INFINITY;
            #pragma unroll
            for (int j = 0; j < 8; j++) m = fmaxf(m, gl[f][j]);
            float s = 0.f;
            #pragma unroll
            for (int j = 0; j < 8; j++) s += __expf(gl[f][j] - m);
            float wv = __expf(gl[f][k] - m) / s;
            wsm[f][k] = wv;
            ws[tid] = wv;
        }
        for (int i = tid; i < 992; i += 256) {   // lse over self_tables v-axis
            int f = i >> 5, c = i & 31;
            float s = 0.f;
            #pragma unroll 8
            for (int v = 0; v < V_; v++) s += __expf(st[(f * V_ + v) * C_ + c]);
            lsf[f][c] = __logf(s);
        }
        __syncthreads();
        if (tid < 32) {
            int c = tid;
            float scl = 0.f;
            #pragma unroll
            for (int j = 0; j < C_; j++) scl += __expf(cl[j]);
            float lse_cl = __logf(scl);
            float s0 = 0.f;
            #pragma unroll 8
            for (int v = 0; v < V_; v++) s0 += __expf(t0[v * C_ + c]);
            float lse_t0 = __logf(s0);
            float acc = cl[c] - lse_cl - lse_t0;
            for (int f = 0; f < 31; f++) acc -= wsm[f][0] * lsf[f][c];
            ws[WS_OFF + c] = acc;
        }
    } else {
        // ---------- pair-gather: 4 samples/block, self-contained ----------
        __shared__ int    xsh[4 * 33];
        __shared__ float  wsh[256];
        __shared__ int    etab[200];
        __shared__ float4 part[7][32];
        __shared__ float  gl[31][8];
        int tid = threadIdx.x;
        int pb  = blockIdx.x - (NBLK_LSE + 1);   // 0..2047
        if (tid < 128) xsh[(tid >> 5) * 33 + (tid & 31)] = x[pb * 128 + tid];
        // local gumbel logits (sl/un are 1 KB, L2-hot after first block)
        if (tid < 248) {
            int f = tid >> 3, k = tid & 7;
            int kmax = min(f + 1, KP_);
            bool valid = (k <= kmax);
            float u = un[tid];
            float g = -__logf(-__logf(u + EPS_) + EPS_);
            gl[f][k] = valid ? (sl[tid] + g) : -INFINITY;
        }
        // analytic entry table (pure ALU)
        if (tid < 200) {
            int q = tid / 25, i = tid % 25;
            int g = d_split[q] + i;
            int packed;
            if (g < d_split[q + 1]) {
                int f = 0, base = 0;
                for (;;) { int cnt = min(f + 1, KP_); if (g < base + cnt) break; base += cnt; f++; }
                int k = g - base;
                packed = ((f * 8 + k + 1) << 20) | ((f * KP_ + k) << 12) | ((f + 1) << 6) | (f - k);
            } else {
                packed = (248 << 20);   // weight=0 pad entry
            }
            etab[tid] = packed;
        }
        __syncthreads();
        if (tid < 248) {
            int f = tid >> 3;
            float m = -INFINITY;
            #pragma unroll
            for (int j = 0; j < 8; j++) m = fmaxf(m, gl[f][j]);
            float s = 0.f;
            #pragma unroll
            for (int j = 0; j < 8; j++) s += __expf(gl[f][j] - m);
            wsh[tid] = __expf(gl[f][tid & 7] - m) / s;
        } else {
            wsh[tid] = 0.f;
        }
        __syncthreads();

        int q  = tid >> 5;
        int r  = (tid >> 3) & 3;
        int c4 = tid & 7;
        const int* xrow = &xsh[r * 33];
        const float* __restrict__ ptb = pt + c4 * 4;
        float4 acc = make_float4(0.f, 0.f, 0.f, 0.f);

        int beg = q * 25;
        #pragma unroll
        for (int ch = 0; ch < 5; ch++) {
            float4 pv[5];
            float  wt[5];
            #pragma unroll
            for (int i = 0; i < 5; i++) {
                int pk = etab[beg + ch * 5 + i];
                int ci = pk & 63, fi = (pk >> 6) & 63;
                int fk = (pk >> 12) & 255, widx = (pk >> 20) & 255;
                int xv = xrow[fi], xc = xrow[ci];
                pv[i] = *(const float4*)(ptb + ((size_t)(fk * V_ + xv) * V_ + xc) * C_);
                wt[i] = wsh[widx];
            }
            #pragma unroll
            for (int i = 0; i < 5; i++) {
                acc.x += wt[i] * pv[i].x; acc.y += wt[i] * pv[i].y;
                acc.z += wt[i] * pv[i].z; acc.w += wt[i] * pv[i].w;
            }
        }

        if (q > 0) part[q - 1][r * 8 + c4] = acc;
        __syncthreads();
        if (q == 0) {
            #pragma unroll
            for (int p = 0; p < 7; p++) {
                float4 pv2 = part[p][r * 8 + c4];
                acc.x += pv2.x; acc.y += pv2.y; acc.z += pv2.z; acc.w += pv2.w;
            }
            ((float4*)(ws + WS_PART))[(pb * 4 + r) * 8 + c4] = acc;
        }
    }
}

// ------------- Kernel 2: fold lse + t0 + self into G, float4 ---------------
__global__ __launch_bounds__(256)
void foldg_kernel(const float* __restrict__ t0, const float* __restrict__ st,
                  float* __restrict__ ws) {
    int idx = blockIdx.x * 256 + threadIdx.x;
    int c4 = idx & 7, v = (idx >> 3) & 63, j = idx >> 9;    // j 0..31
    int nk = min(KP_, 31 - j);
    const float4* lse4 = (const float4*)(ws + WS_LSE);
    float4 g;
    if (j == 0) {
        g = ((const float4*)t0)[v * 8 + c4];
    } else {
        float w0 = ws[(j - 1) * 8];
        float4 sv = ((const float4*)st)[((j - 1) * V_ + v) * 8 + c4];
        g.x = w0 * sv.x; g.y = w0 * sv.y; g.z = w0 * sv.z; g.w = w0 * sv.w;
    }
    for (int k = 0; k < nk; k++) {
        int f = j + k;
        float wv = ws[f * 8 + k + 1];
        int iq = ((f * KP_ + k) * V_ + v) * 8 + c4;
        float4 sa = lse4[iq];
        float4 sb = lse4[1 * LSE_BANK4 + iq];
        float4 sc = lse4[2 * LSE_BANK4 + iq];
        float4 sd = lse4[3 * LSE_BANK4 + iq];
        g.x -= wv * __logf(sa.x + sb.x + sc.x + sd.x);
        g.y -= wv * __logf(sa.y + sb.y + sc.y + sd.y);
        g.z -= wv * __logf(sa.z + sb.z + sc.z + sd.z);
        g.w -= wv * __logf(sa.w + sb.w + sc.w + sd.w);
    }
    ((float4*)(ws + WS_G))[idx] = g;
}

// ------------- Kernel 3: G-table epilogue (L2-resident) ---------------------
// 32 samples/block, 256 blocks: acc = part + offc + sum_j G[j][x_j]
__global__ __launch_bounds__(256)
void maing_kernel(const int* __restrict__ x, const float* __restrict__ ws,
                  float* __restrict__ out) {
    __shared__ int    xsh[32][33];
    __shared__ float4 offv[8];
    int tid = threadIdx.x;
    int rbase = blockIdx.x * 32;
    for (int i = tid; i < 1024; i += 256) {
        int rr = i >> 5, jj = i & 31;
        xsh[rr][jj] = x[(rbase + rr) * 32 + jj];
    }
    if (tid < 8) offv[tid] = ((const float4*)(ws + WS_OFF))[tid];
    __syncthreads();
    int r = tid >> 3, c4 = tid & 7;
    const float4* __restrict__ G4 = (const float4*)(ws + WS_G);
    float4 acc = ((const float4*)(ws + WS_PART))[(rbase + r) * 8 + c4];
    float4 ov = offv[c4];
    acc.x += ov.x; acc.y += ov.y; acc.z += ov.z; acc.w += ov.w;
    #pragma unroll 8
    for (int j = 0; j < 32; j++) {
        float4 gv = G4[(j * V_ + xsh[r][j]) * 8 + c4];
        acc.x += gv.x; acc.y += gv.y; acc.z += gv.z; acc.w += gv.w;
    }
    ((float4*)out)[(rbase + r) * 8 + c4] = acc;
}

extern "C" void kernel_launch(void* const* d_in, const int* in_sizes, int n_in,
                              void* d_out, int out_size, void* d_ws, size_t ws_size,
                              hipStream_t stream) {
    const int*   x   = (const int*)  d_in[0];
    // d_in[1] = training (unused)
    const float* cl  = (const float*)d_in[2];
    const float* t0  = (const float*)d_in[3];
    const float* st  = (const float*)d_in[4];
    const float* pt  = (const float*)d_in[5];
    const float* sl  = (const float*)d_in[6];
    const float* un  = (const float*)d_in[7];
    // d_in[8] cond_index, d_in[9] valid_mask: deterministic, computed analytically
    float* ws  = (float*)d_ws;
    float* out = (float*)d_out;

    fused_kernel<<<NBLK_LSE + 1 + NBLK_PAIR, 256, 0, stream>>>(x, pt, cl, t0, st, sl, un, ws);
    foldg_kernel<<<64, 256, 0, stream>>>(t0, st, ws);
    maing_kernel<<<256, 256, 0, stream>>>(x, ws, out);
}

// Round 8
// 220.454 us; speedup vs baseline: 1.0482x; 1.0125x over previous
//
#include <hip/hip_runtime.h>
#include <math.h>

// Problem constants
#define B_  8192
#define F_  32
#define V_  64
#define C_  32
#define KP_ 7
#define EPS_ 1e-6f

typedef float f4 __attribute__((ext_vector_type(4)));

// ws layout (floats):
//  [0,248)           : w[f][k]  (31 x 8 gumbel-softmax weights); [248,256) zeros
//  [256,288)         : offc[c]
//  [512,66048)       : G[j][v][c]   (folded t0/self/pair-lse table, 256 KB)
//  [66048,1843712)   : partial exp-sums, 4 banks of [fk][xc][c];
//                      foldg does log(b0+b1+b2+b3)
//  [1843712,3940864) : pair partials, [sample][group][c] float4s (8 MB)
#define WS_OFF  256
#define WS_G    512
#define WS_LSE  66048
#define LSE_BANK4 111104    // bank stride in float4 units (217*64*8)
#define WS_PART 1843712

// Fused kernel decomposition:
//  blocks [0,868)        : lse streaming (fk, quarter-of-a-axis), NT loads
//  block  868            : prep (weights to ws, offc)
//  blocks [869, 869+2048): pair-gather, ENTRY-MAJOR XCD-AFFINE:
//                          group g = pb&7 (stride-8 XCD round-robin is
//                          preserved under the +869 offset), chunk = pb>>3;
//                          32 samples x the group's 25 entries.
#define NBLK_LSE 868
#define NBLK_PAIR 2048

__device__ const int d_split[9] = {0, 25, 50, 74, 99, 123, 148, 172, 196};

// ---- Kernel 1 (fused): NT lse stream + prep + XCD-affine pair gather.
// Round-7 evidence: NT stream stopped L2 pollution (fused 76->68 us).
// Round-6 evidence: entry-major affinity helps the gather (~45 us alone)
// but serialization cost more than it saved. This round combines them:
// the NT stream passes through L2 evict-first, so the per-XCD hot
// sub-tables of the entry-major gather stay resident DURING the overlap.
__global__ __launch_bounds__(256)
void fused_kernel(const int* __restrict__ x, const float* __restrict__ pt,
                  const float* __restrict__ cl, const float* __restrict__ t0,
                  const float* __restrict__ st, const float* __restrict__ sl,
                  const float* __restrict__ un, float* __restrict__ ws) {
    if (blockIdx.x < NBLK_LSE) {
        // ---------- lse: exp-sum over pair self-axis, NT contiguous stream -
        int fk = blockIdx.x >> 2;     // 0..216
        int qa = blockIdx.x & 3;      // which 16-slice of the a-axis
        int t  = threadIdx.x;
        const f4* __restrict__ p =
            (const f4*)(pt + (size_t)fk * (V_ * V_ * C_)
                           + (size_t)qa * 16 * (V_ * C_));
        const f4* p0 = p + t;
        const f4* p1 = p + 256 + t;
        f4 s0 = (f4)(0.f);
        f4 s1 = (f4)(0.f);
        #pragma unroll 4
        for (int a = 0; a < 16; a++) {
            f4 l0 = __builtin_nontemporal_load(p0 + a * 512);
            f4 l1 = __builtin_nontemporal_load(p1 + a * 512);
            s0.x += __expf(l0.x); s0.y += __expf(l0.y);
            s0.z += __expf(l0.z); s0.w += __expf(l0.w);
            s1.x += __expf(l1.x); s1.y += __expf(l1.y);
            s1.z += __expf(l1.z); s1.w += __expf(l1.w);
        }
        f4* lseP = (f4*)(ws + WS_LSE) + (size_t)qa * LSE_BANK4;
        __builtin_nontemporal_store(s0, lseP + fk * 512 + t);
        __builtin_nontemporal_store(s1, lseP + fk * 512 + 256 + t);
    } else if (blockIdx.x == NBLK_LSE) {
        // ---------- prep: ws weights (foldg) + offc (mainG) ----------
        __shared__ float gl[31][8];
        __shared__ float wsm[31][8];
        __shared__ float lsf[31][32];
        int tid = threadIdx.x;
        if (tid < 248) {
            int f = tid >> 3, k = tid & 7;
            int kmax = min(f + 1, KP_);
            bool valid = (k <= kmax);
            float u = un[tid];
            float g = -__logf(-__logf(u + EPS_) + EPS_);
            gl[f][k] = valid ? (sl[tid] + g) : -INFINITY;
        } else {
            ws[tid] = 0.f;
        }
        __syncthreads();
        if (tid < 248) {
            int f = tid >> 3, k = tid & 7;
            float m = -INFINITY;
            #pragma unroll
            for (int j = 0; j < 8; j++) m = fmaxf(m, gl[f][j]);
            float s = 0.f;
            #pragma unroll
            for (int j = 0; j < 8; j++) s += __expf(gl[f][j] - m);
            float wv = __expf(gl[f][k] - m) / s;
            wsm[f][k] = wv;
            ws[tid] = wv;
        }
        for (int i = tid; i < 992; i += 256) {   // lse over self_tables v-axis
            int f = i >> 5, c = i & 31;
            float s = 0.f;
            #pragma unroll 8
            for (int v = 0; v < V_; v++) s += __expf(st[(f * V_ + v) * C_ + c]);
            lsf[f][c] = __logf(s);
        }
        __syncthreads();
        if (tid < 32) {
            int c = tid;
            float scl = 0.f;
            #pragma unroll
            for (int j = 0; j < C_; j++) scl += __expf(cl[j]);
            float lse_cl = __logf(scl);
            float s0 = 0.f;
            #pragma unroll 8
            for (int v = 0; v < V_; v++) s0 += __expf(t0[v * C_ + c]);
            float lse_t0 = __logf(s0);
            float acc = cl[c] - lse_cl - lse_t0;
            for (int f = 0; f < 31; f++) acc -= wsm[f][0] * lsf[f][c];
            ws[WS_OFF + c] = acc;
        }
    } else {
        // ---------- pair-gather: entry-major, XCD-affine ----------
        __shared__ int   xsh[32][33];
        __shared__ float wsh[256];
        __shared__ int   etab[200];
        __shared__ float gl[31][8];
        int tid = threadIdx.x;
        int pb    = blockIdx.x - (NBLK_LSE + 1);   // 0..2047
        int g     = pb & 7;                        // entry group == XCD slot
        int chunk = pb >> 3;                       // 0..255
        int s0    = chunk * 32;
        for (int i = tid; i < 1024; i += 256)
            xsh[i >> 5][i & 31] = x[s0 * 32 + i];
        // local gumbel logits (sl/un are 1 KB, L2-hot after first block)
        if (tid < 248) {
            int f = tid >> 3, k = tid & 7;
            int kmax = min(f + 1, KP_);
            bool valid = (k <= kmax);
            float u = un[tid];
            float gg = -__logf(-__logf(u + EPS_) + EPS_);
            gl[f][k] = valid ? (sl[tid] + gg) : -INFINITY;
        }
        // analytic entry table (pure ALU)
        if (tid < 200) {
            int q = tid / 25, i = tid % 25;
            int e = d_split[q] + i;
            int packed;
            if (e < d_split[q + 1]) {
                int f = 0, base = 0;
                for (;;) { int cnt = min(f + 1, KP_); if (e < base + cnt) break; base += cnt; f++; }
                int k = e - base;
                packed = ((f * 8 + k + 1) << 20) | ((f * KP_ + k) << 12) | ((f + 1) << 6) | (f - k);
            } else {
                packed = (248 << 20);   // weight=0 pad entry
            }
            etab[tid] = packed;
        }
        __syncthreads();
        if (tid < 248) {
            int f = tid >> 3;
            float m = -INFINITY;
            #pragma unroll
            for (int j = 0; j < 8; j++) m = fmaxf(m, gl[f][j]);
            float s = 0.f;
            #pragma unroll
            for (int j = 0; j < 8; j++) s += __expf(gl[f][j] - m);
            wsh[tid] = __expf(gl[f][tid & 7] - m) / s;
        } else {
            wsh[tid] = 0.f;
        }
        __syncthreads();

        int s  = tid >> 3;          // 0..31: sample within chunk
        int c4 = tid & 7;
        const int* xrow = xsh[s];
        const float* __restrict__ ptb = pt + c4 * 4;
        float4 acc = make_float4(0.f, 0.f, 0.f, 0.f);

        int beg = g * 25;
        #pragma unroll
        for (int ch = 0; ch < 5; ch++) {
            float4 pv[5];
            float  wt[5];
            #pragma unroll
            for (int i = 0; i < 5; i++) {
                int pk = etab[beg + ch * 5 + i];
                int ci = pk & 63, fi = (pk >> 6) & 63;
                int fk = (pk >> 12) & 255, widx = (pk >> 20) & 255;
                int xv = xrow[fi], xc = xrow[ci];
                pv[i] = *(const float4*)(ptb + ((size_t)(fk * V_ + xv) * V_ + xc) * C_);
                wt[i] = wsh[widx];
            }
            #pragma unroll
            for (int i = 0; i < 5; i++) {
                acc.x += wt[i] * pv[i].x; acc.y += wt[i] * pv[i].y;
                acc.z += wt[i] * pv[i].z; acc.w += wt[i] * pv[i].w;
            }
        }
        // partial: [sample][group][c4] float4
        ((float4*)(ws + WS_PART))[(size_t)(s0 + s) * 64 + g * 8 + c4] = acc;
    }
}

// ------------- Kernel 2: fold lse + t0 + self into G, float4 ---------------
__global__ __launch_bounds__(256)
void foldg_kernel(const float* __restrict__ t0, const float* __restrict__ st,
                  float* __restrict__ ws) {
    int idx = blockIdx.x * 256 + threadIdx.x;
    int c4 = idx & 7, v = (idx >> 3) & 63, j = idx >> 9;    // j 0..31
    int nk = min(KP_, 31 - j);
    const float4* lse4 = (const float4*)(ws + WS_LSE);
    float4 g;
    if (j == 0) {
        g = ((const float4*)t0)[v * 8 + c4];
    } else {
        float w0 = ws[(j - 1) * 8];
        float4 sv = ((const float4*)st)[((j - 1) * V_ + v) * 8 + c4];
        g.x = w0 * sv.x; g.y = w0 * sv.y; g.z = w0 * sv.z; g.w = w0 * sv.w;
    }
    for (int k = 0; k < nk; k++) {
        int f = j + k;
        float wv = ws[f * 8 + k + 1];
        int iq = ((f * KP_ + k) * V_ + v) * 8 + c4;
        float4 sa = lse4[iq];
        float4 sb = lse4[1 * LSE_BANK4 + iq];
        float4 sc = lse4[2 * LSE_BANK4 + iq];
        float4 sd = lse4[3 * LSE_BANK4 + iq];
        g.x -= wv * __logf(sa.x + sb.x + sc.x + sd.x);
        g.y -= wv * __logf(sa.y + sb.y + sc.y + sd.y);
        g.z -= wv * __logf(sa.z + sb.z + sc.z + sd.z);
        g.w -= wv * __logf(sa.w + sb.w + sc.w + sd.w);
    }
    ((float4*)(ws + WS_G))[idx] = g;
}

// ---- Kernel 3: epilogue -- sum 8 group partials + offc + G gathers --------
__global__ __launch_bounds__(256)
void maing_kernel(const int* __restrict__ x, const float* __restrict__ ws,
                  float* __restrict__ out) {
    __shared__ int    xsh[32][33];
    __shared__ float4 offv[8];
    int tid = threadIdx.x;
    int rbase = blockIdx.x * 32;
    for (int i = tid; i < 1024; i += 256) {
        int rr = i >> 5, jj = i & 31;
        xsh[rr][jj] = x[(rbase + rr) * 32 + jj];
    }
    if (tid < 8) offv[tid] = ((const float4*)(ws + WS_OFF))[tid];
    __syncthreads();
    int r = tid >> 3, c4 = tid & 7;
    const float4* __restrict__ G4 = (const float4*)(ws + WS_G);
    float4 acc = offv[c4];
    const float4* __restrict__ pp =
        (const float4*)(ws + WS_PART) + (size_t)(rbase + r) * 64 + c4;
    #pragma unroll
    for (int g = 0; g < 8; g++) {
        float4 t = pp[g * 8];
        acc.x += t.x; acc.y += t.y; acc.z += t.z; acc.w += t.w;
    }
    #pragma unroll 8
    for (int j = 0; j < 32; j++) {
        float4 gv = G4[(j * V_ + xsh[r][j]) * 8 + c4];
        acc.x += gv.x; acc.y += gv.y; acc.z += gv.z; acc.w += gv.w;
    }
    ((float4*)out)[(rbase + r) * 8 + c4] = acc;
}

extern "C" void kernel_launch(void* const* d_in, const int* in_sizes, int n_in,
                              void* d_out, int out_size, void* d_ws, size_t ws_size,
                              hipStream_t stream) {
    const int*   x   = (const int*)  d_in[0];
    // d_in[1] = training (unused)
    const float* cl  = (const float*)d_in[2];
    const float* t0  = (const float*)d_in[3];
    const float* st  = (const float*)d_in[4];
    const float* pt  = (const float*)d_in[5];
    const float* sl  = (const float*)d_in[6];
    const float* un  = (const float*)d_in[7];
    // d_in[8] cond_index, d_in[9] valid_mask: deterministic, computed analytically
    float* ws  = (float*)d_ws;
    float* out = (float*)d_out;

    fused_kernel<<<NBLK_LSE + 1 + NBLK_PAIR, 256, 0, stream>>>(x, pt, cl, t0, st, sl, un, ws);
    foldg_kernel<<<64, 256, 0, stream>>>(t0, st, ws);
    maing_kernel<<<256, 256, 0, stream>>>(x, ws, out);
}